// Round 5
// baseline (234.855 us; speedup 1.0000x reference)
//
#include <hip/hip_runtime.h>
#include <math.h>

#define HH 384
#define H2 (HH*HH)
#define NIMG 32
#define KK 378
#define NSH 49
#define NTOTD 4572288.0   // 32*378*378

// ---- correlation geometry: 1 row x 14 cols per thread ----
#define SEGW 14
#define NSEG 27            // 27*14 = 378
#define NSLOT 9            // rows per tile
#define TRR 9              // tile rows
#define NTIL 42            // 378/9
#define NB2 (NIMG*NTIL)    // 1344 blocks
#define NACT (NSEG*NSLOT)  // 243 active threads
#define SROWS (TRR+6)      // 15 staged rows
#define LSF 388            // LDS float stride (384+4)

// ---- workspace layout (float units; double regions 8B-aligned) ----
#define OFF_PART   0                         // [149][1344] float
#define OFF_ROWOUT (OFF_PART + 149*NB2)      // [12288][28] float
#define OFF_WPART  (OFF_ROWOUT + 12288*28)   // [196][32] double (12544 fl)
#define OFF_CORRD  (OFF_WPART + 12544)       // [149] double (298 fl)

// Canonical GCN wave64 sum: result in lane 63.
__device__ __forceinline__ float wred(float x) {
    x += __int_as_float(__builtin_amdgcn_update_dpp(0, __float_as_int(x), 0x111, 0xf, 0xf, true));
    x += __int_as_float(__builtin_amdgcn_update_dpp(0, __float_as_int(x), 0x112, 0xf, 0xf, true));
    x += __int_as_float(__builtin_amdgcn_update_dpp(0, __float_as_int(x), 0x114, 0xf, 0xf, true));
    x += __int_as_float(__builtin_amdgcn_update_dpp(0, __float_as_int(x), 0x118, 0xf, 0xf, true));
    x += __int_as_float(__builtin_amdgcn_update_dpp(0, __float_as_int(x), 0x142, 0xa, 0xf, true));
    x += __int_as_float(__builtin_amdgcn_update_dpp(0, __float_as_int(x), 0x143, 0xc, 0xf, true));
    return x;
}

// ---------------- correlation trio ----------------
// MODE 0: acc = sum t*p (+ Sp, Sp2)   -> part rows 0..48, 147, 148
// MODE 1: acc = sum m*p               -> part rows 49..97
// MODE 2: acc = sum |t-p|             -> part rows 98..146
template<int MODE>
__global__ __launch_bounds__(256, 4) void k_corrq(
    const float* __restrict__ pred, const float* __restrict__ targ,
    float* __restrict__ part)
{
    __shared__ float lds[SROWS * LSF];       // 23280 B
    __shared__ float red[51][4];

    const int bid = blockIdx.x;
    const int img = bid / NTIL;
    const int tile = bid - img * NTIL;
    const int r0 = tile * TRR;
    const int tid = threadIdx.x;
    const int lane = tid & 63;
    const int wave = tid >> 6;

    // stage rows r0..r0+14, full width, float4
    const float* timg = targ + (size_t)img * H2;
    for (int i = tid; i < SROWS * 96; i += 256) {
        int r = i / 96, c4 = (i - r * 96) * 4;
        float4 t4 = *reinterpret_cast<const float4*>(timg + (r0 + r) * HH + c4);
        if (MODE == 1) {
            t4.x = t4.x > 5.0f ? 1.0f : 0.0f;
            t4.y = t4.y > 5.0f ? 1.0f : 0.0f;
            t4.z = t4.z > 5.0f ? 1.0f : 0.0f;
            t4.w = t4.w > 5.0f ? 1.0f : 0.0f;
        }
        *reinterpret_cast<float4*>(&lds[r * LSF + c4]) = t4;
    }

    const bool valid = tid < NACT;
    const int seg  = valid ? tid % NSEG : NSEG - 1;
    const int slot = valid ? tid / NSEG : NSLOT - 1;
    const int c0 = seg * SEGW;

    float p_[SEGW];
    float sp = 0.0f, sp2 = 0.0f;
    {
        const float* prow = pred + (size_t)img * H2 + (size_t)(3 + r0 + slot) * HH + 3 + c0;
#pragma unroll
        for (int c = 0; c < SEGW; ++c) {
            float pv = prow[c];
            p_[c] = pv;
            if (MODE == 0) { sp += pv; sp2 = fmaf(pv, pv, sp2); }
        }
    }

    float acc[NSH];
#pragma unroll
    for (int i = 0; i < NSH; ++i) acc[i] = 0.0f;

    __syncthreads();

#pragma unroll
    for (int u = 0; u < 7; ++u) {
        float win[SEGW + 6];
        const int wb = (slot + u) * LSF + c0;
#pragma unroll
        for (int c = 0; c < SEGW + 6; ++c) win[c] = lds[wb + c];
#pragma unroll
        for (int c = 0; c < SEGW; ++c) {
            const float pv = p_[c];
#pragma unroll
            for (int v = 0; v < 7; ++v) {
                if (MODE == 2) acc[u * 7 + v] += fabsf(win[v + c] - pv);
                else           acc[u * 7 + v] = fmaf(win[v + c], pv, acc[u * 7 + v]);
            }
        }
    }

    const float vf = valid ? 1.0f : 0.0f;
#pragma unroll
    for (int i = 0; i < NSH; ++i) {
        float r = wred(acc[i] * vf);
        if (lane == 63) red[i][wave] = r;
    }
    if (MODE == 0) {
        float rs = wred(sp * vf), rs2 = wred(sp2 * vf);
        if (lane == 63) { red[49][wave] = rs; red[50][wave] = rs2; }
    }
    __syncthreads();

    const int nred = (MODE == 0) ? 51 : 49;
    if (tid < nred) {
        int row = (MODE == 0) ? (tid < 49 ? tid : 147 + (tid - 49))
                              : (MODE == 1 ? 49 + tid : 98 + tid);
        part[(size_t)row * NB2 + bid] =
            red[tid][0] + red[tid][1] + red[tid][2] + red[tid][3];
    }
}

// ---------------- k_rows: per-row sums + compressed borders ----------------
// rowout[row][28]: [0..3]=R_q ; [4+x*2 .. 5+x*2] = (t,m) x<6 ; [16+k*2 ..] = (t,m) k=x-378
__global__ __launch_bounds__(256) void k_rows(
    const float* __restrict__ targ, float* __restrict__ rowout)
{
    const int tid = threadIdx.x;
    const int w = tid >> 6, lane = tid & 63;
    const int row = blockIdx.x * 4 + w;
    const int img = row / HH, y = row - img * HH;
    const float* tr = targ + (size_t)img * H2 + (size_t)y * HH;
    float* ro = rowout + (size_t)row * 28;

    float s0 = 0, s1 = 0, s2 = 0, s3 = 0;
#pragma unroll
    for (int j = 0; j < 6; ++j) {
        int x = lane + 64 * j;
        float t = tr[x];
        float m = t > 5.0f ? 1.0f : 0.0f;
        s0 += t; s1 = fmaf(t, t, s1); s2 = fmaf(t, m, s2); s3 += m;
        if (j == 0 && lane < 6) { ro[4 + x * 2] = t; ro[5 + x * 2] = m; }
        if (j == 5 && lane >= 58) {
            int k = x - 378;
            ro[16 + k * 2] = t; ro[17 + k * 2] = m;
        }
    }
    s0 = wred(s0); s1 = wred(s1); s2 = wred(s2); s3 = wred(s3);
    if (lane == 63) { ro[0] = s0; ro[1] = s1; ro[2] = s2; ro[3] = s3; }
}

// ---------------- k_cols: per-(img,v) window sums -> wpart ----------------
__global__ __launch_bounds__(384) void k_cols(
    const float* __restrict__ rowout, double* __restrict__ wpart)
{
    __shared__ double sd[384][4];
    __shared__ float hb[6][4], tb[6][4];
    const int img = blockIdx.x / 7, v = blockIdx.x - img * 7;
    const int y = threadIdx.x;

    const float* rp = rowout + ((size_t)img * HH + y) * 28;
    float4 r4[7];
#pragma unroll
    for (int i = 0; i < 7; ++i) r4[i] = reinterpret_cast<const float4*>(rp)[i];
    const float* rf = reinterpret_cast<const float*>(r4);

    float rw[4];
#pragma unroll
    for (int q = 0; q < 4; ++q) rw[q] = rf[q];
    for (int j = 0; j < v; ++j) {
        float t = rf[4 + j * 2], m = rf[5 + j * 2];
        rw[0] -= t; rw[1] -= t * t; rw[2] -= t * m; rw[3] -= m;
    }
    for (int k = v; k < 6; ++k) {
        float t = rf[16 + k * 2], m = rf[17 + k * 2];
        rw[0] -= t; rw[1] -= t * t; rw[2] -= t * m; rw[3] -= m;
    }

#pragma unroll
    for (int q = 0; q < 4; ++q) sd[y][q] = (double)rw[q];
    if (y < 6)
#pragma unroll
        for (int q = 0; q < 4; ++q) hb[y][q] = rw[q];
    if (y >= KK)
#pragma unroll
        for (int q = 0; q < 4; ++q) tb[y - KK][q] = rw[q];
    __syncthreads();

    for (int s = 192; s >= 3; s >>= 1) {
        if (y < s)
#pragma unroll
            for (int q = 0; q < 4; ++q) sd[y][q] += sd[y + s][q];
        __syncthreads();
    }

    if (y < 28) {
        int u = y >> 2, q = y & 3;
        double a = sd[0][q] + sd[1][q] + sd[2][q];
        for (int j = 0; j < u; ++j) a -= (double)hb[j][q];
        for (int k = u; k < 6; ++k) a -= (double)tb[k][q];
        wpart[((size_t)(u * 7 + v) * 4 + q) * 32 + img] = a;
    }
}

// ---------------- k_red: part[149][1344] -> corrD[149] doubles ----------------
__global__ __launch_bounds__(256) void k_red(
    const float* __restrict__ part, double* __restrict__ corrD)
{
    __shared__ double sd[256];
    const int q = blockIdx.x;
    const int t = threadIdx.x;
    const float* pp = part + (size_t)q * NB2;
    double a = (double)pp[t] + (double)pp[t + 256] + (double)pp[t + 512]
             + (double)pp[t + 768] + (double)pp[t + 1024];
    if (t < NB2 - 1280) a += (double)pp[t + 1280];
    sd[t] = a;
    __syncthreads();
    for (int s = 128; s > 0; s >>= 1) {
        if (t < s) sd[t] += sd[t + s];
        __syncthreads();
    }
    if (t == 0) corrD[q] = sd[0];
}

// ---------------- k_fin: Wd, cmse argmin, cPSNR, MAE ----------------
__global__ __launch_bounds__(256) void k_fin(
    const double* __restrict__ corrD, const double* __restrict__ wpart,
    float* __restrict__ out)
{
    __shared__ double Wd[NSH][4];
    __shared__ double cm[NSH];
    const int t = threadIdx.x;

    if (t < 196) {
        const double* wp = wpart + (size_t)t * 32;
        double a0 = 0, a1 = 0;
#pragma unroll
        for (int i = 0; i < 32; i += 2) { a0 += wp[i]; a1 += wp[i + 1]; }
        Wd[t >> 2][t & 3] = a0 + a1;
    }
    __syncthreads();
    if (t < NSH) {
        double tp = corrD[t], mp = corrD[49 + t];
        double Sp = corrD[147], Sp2 = corrD[148];
        double b = (Wd[t][2] - mp) / Wd[t][3];
        double s1 = Wd[t][0] - Sp;
        double s2t = Wd[t][1] - 2.0 * tp + Sp2;
        cm[t] = (s2t - 2.0 * b * s1 + NTOTD * b * b) / Wd[t][3];
    }
    __syncthreads();
    if (t == 0) {
        double best = cm[0]; int bi = 0;
        for (int s = 1; s < NSH; ++s)
            if (cm[s] < best) { best = cm[s]; bi = s; }   // first-min (jnp.argmin)
        out[0] = (float)(-10.0 * log10(best));
        out[1] = (float)(corrD[98 + bi] / NTOTD);
    }
}

extern "C" void kernel_launch(void* const* d_in, const int* in_sizes, int n_in,
                              void* d_out, int out_size, void* d_ws, size_t ws_size,
                              hipStream_t stream) {
    const float* pred = (const float*)d_in[0];
    const float* targ = (const float*)d_in[1];
    float* w = (float*)d_ws;                 // needs ~2.23 MB
    float*  part   = w + OFF_PART;
    float*  rowout = w + OFF_ROWOUT;
    double* wpart  = (double*)(w + OFF_WPART);
    double* corrD  = (double*)(w + OFF_CORRD);
    float* out = (float*)d_out;

    k_corrq<0><<<NB2, 256, 0, stream>>>(pred, targ, part);
    k_corrq<1><<<NB2, 256, 0, stream>>>(pred, targ, part);
    k_corrq<2><<<NB2, 256, 0, stream>>>(pred, targ, part);
    k_rows<<<12288 / 4, 256, 0, stream>>>(targ, rowout);
    k_cols<<<NIMG * 7, 384, 0, stream>>>(rowout, wpart);
    k_red<<<149, 256, 0, stream>>>(part, corrD);
    k_fin<<<1, 256, 0, stream>>>(corrD, wpart, out);
}